// Round 1
// baseline (141.973 us; speedup 1.0000x reference)
//
#include <hip/hip_runtime.h>

// Chamfer distance: B=16 clouds, N=4096 points, D=3, fp32.
// batch is sorted equal segments -> dense batch is a pure reshape.
// d2(i,j) = |x_i|^2 + (|y_j|^2 - 2 x_i.y_j); x_i^2 is constant over the
// min_j, so inner loop is 3 fma + 1 min per pair (4 VALU/pair).

#define BB 16
#define NN 4096
#define T  256
#define M  2            // x points per thread
#define XTILES (NN / (T * M))   // 8 -> grid 8*16*2 = 256 blocks (1/CU)

__global__ __launch_bounds__(T) void chamfer_kernel(
    const float* __restrict__ pred,
    const float* __restrict__ target,
    float* __restrict__ out)
{
    // y staged as {-2y0, -2y1, -2y2, |y|^2} : 4096 * 16B = 64 KiB LDS
    __shared__ float4 ys[NN];

    const int b   = blockIdx.y;
    const int dir = blockIdx.z;
    const float* xb = (dir ? target : pred)   + (size_t)b * NN * 3;
    const float* yb = (dir ? pred   : target) + (size_t)b * NN * 3;

    for (int j = threadIdx.x; j < NN; j += T) {
        float y0 = yb[3 * j + 0];
        float y1 = yb[3 * j + 1];
        float y2 = yb[3 * j + 2];
        ys[j] = make_float4(-2.f * y0, -2.f * y1, -2.f * y2,
                            fmaf(y0, y0, fmaf(y1, y1, y2 * y2)));
    }
    __syncthreads();

    float x0[M], x1[M], x2[M], xsq[M], mn[M];
    const int xbase = blockIdx.x * (T * M);
#pragma unroll
    for (int m = 0; m < M; ++m) {
        int xi = xbase + threadIdx.x + m * T;
        float a = xb[3 * xi + 0];
        float c = xb[3 * xi + 1];
        float d = xb[3 * xi + 2];
        x0[m] = a; x1[m] = c; x2[m] = d;
        xsq[m] = fmaf(a, a, fmaf(c, c, d * d));
        mn[m]  = 3.402823466e38f;
    }

    for (int j = 0; j < NN; j += 8) {
#pragma unroll
        for (int u = 0; u < 8; ++u) {
            const float4 y = ys[j + u];       // broadcast read, conflict-free
#pragma unroll
            for (int m = 0; m < M; ++m) {
                float f = fmaf(x2[m], y.z, y.w);
                f = fmaf(x1[m], y.y, f);
                f = fmaf(x0[m], y.x, f);
                mn[m] = fminf(mn[m], f);
            }
        }
    }

    // per-point min d2 = xsq + mn ; sum locally then one atomic per block
    float s = 0.f;
#pragma unroll
    for (int m = 0; m < M; ++m) s += mn[m] + xsq[m];

#pragma unroll
    for (int off = 32; off > 0; off >>= 1)
        s += __shfl_down(s, off, 64);

    __shared__ float wsum[T / 64];
    if ((threadIdx.x & 63) == 0) wsum[threadIdx.x >> 6] = s;
    __syncthreads();
    if (threadIdx.x == 0) {
        float t = 0.f;
#pragma unroll
        for (int w = 0; w < T / 64; ++w) t += wsum[w];
        atomicAdd(out, t * (1.0f / (BB * NN)));
    }
}

extern "C" void kernel_launch(void* const* d_in, const int* in_sizes, int n_in,
                              void* d_out, int out_size, void* d_ws, size_t ws_size,
                              hipStream_t stream) {
    const float* pred   = (const float*)d_in[0];
    const float* target = (const float*)d_in[1];
    // d_in[2] (batch, int64) is ignored: sorted equal-size segments by construction.
    float* out = (float*)d_out;

    hipMemsetAsync(out, 0, sizeof(float), stream);   // graph-capture safe
    dim3 grid(XTILES, BB, 2);
    chamfer_kernel<<<grid, T, 0, stream>>>(pred, target, out);
}

// Round 2
// 104.614 us; speedup vs baseline: 1.3571x; 1.3571x over previous
//
#include <hip/hip_runtime.h>

// Chamfer distance: B=16 clouds, N=4096 points, D=3, fp32.
// batch is sorted equal segments -> dense batch is a pure reshape.
// d2(i,j) = xsq_i + (yw_j - 2 x_i.y_j); xsq_i constant over min_j -> added
// after the min. Inner loop: 3 fma + shared min3 per pair (3.625 VALU/pair).
//
// R2 restructure: M=8 x/thread (amortize LDS broadcast over 32 VALU cyc),
// y split 8 ways (grid 512 = 2 blocks/CU = 2 waves/SIMD), cross-block min
// via atomicMin on uint bit patterns (d2 clamped >= 0), tiny reduce kernel.

#define BB 16
#define NN 4096
#define T  256
#define M  8                    // x points per thread
#define S  8                    // y splits
#define YC (NN / S)             // 512 y per block
#define XT (NN / (T * M))       // 2 x-tiles -> grid 2*16*16 = 512 blocks

__global__ __launch_bounds__(T) void chamfer_partial(
    const float* __restrict__ pred,
    const float* __restrict__ target,
    unsigned int* __restrict__ pmin)   // 2*BB*NN uints, pre-set to 0x7f7f7f7f
{
    __shared__ float4 ys[YC];          // 8 KiB

    const int b   = blockIdx.y;
    const int dir = blockIdx.z >> 3;
    const int yc  = blockIdx.z & 7;
    const float* xb = (dir ? target : pred) + (size_t)b * NN * 3;
    const float* yb = (dir ? pred : target) + (size_t)b * NN * 3 + (size_t)yc * YC * 3;

    for (int j = threadIdx.x; j < YC; j += T) {
        float y0 = yb[3 * j + 0];
        float y1 = yb[3 * j + 1];
        float y2 = yb[3 * j + 2];
        ys[j] = make_float4(-2.f * y0, -2.f * y1, -2.f * y2,
                            fmaf(y0, y0, fmaf(y1, y1, y2 * y2)));
    }
    __syncthreads();

    float x0[M], x1[M], x2[M], xsq[M], mn[M];
    const int xbase = blockIdx.x * (T * M);
#pragma unroll
    for (int m = 0; m < M; ++m) {
        int xi = xbase + threadIdx.x + m * T;
        float a = xb[3 * xi + 0];
        float c = xb[3 * xi + 1];
        float d = xb[3 * xi + 2];
        x0[m] = a; x1[m] = c; x2[m] = d;
        xsq[m] = fmaf(a, a, fmaf(c, c, d * d));
        mn[m]  = 3.402823466e38f;
    }

#pragma unroll 4
    for (int j = 0; j < YC; j += 2) {
        const float4 ya = ys[j];
        const float4 yv = ys[j + 1];
#pragma unroll
        for (int m = 0; m < M; ++m) {
            float fa = fmaf(x0[m], ya.x, fmaf(x1[m], ya.y, fmaf(x2[m], ya.z, ya.w)));
            float fb = fmaf(x0[m], yv.x, fmaf(x1[m], yv.y, fmaf(x2[m], yv.z, yv.w)));
            mn[m] = fminf(fminf(mn[m], fa), fb);   // -> v_min3_f32
        }
    }

    const int obase = dir * (BB * NN) + b * NN + xbase + threadIdx.x;
#pragma unroll
    for (int m = 0; m < M; ++m) {
        float v = fmaxf(mn[m] + xsq[m], 0.f);      // true d2 >= 0; uint order ok
        atomicMin(&pmin[obase + m * T], __float_as_uint(v));
    }
}

#define TOTX (2 * BB * NN)   // 131072

__global__ __launch_bounds__(256) void chamfer_reduce(
    const float* __restrict__ pmin, float* __restrict__ out)
{
    float s = 0.f;
    for (int i = blockIdx.x * 256 + threadIdx.x; i < TOTX; i += gridDim.x * 256)
        s += pmin[i];
#pragma unroll
    for (int off = 32; off > 0; off >>= 1)
        s += __shfl_down(s, off, 64);
    __shared__ float wsum[4];
    if ((threadIdx.x & 63) == 0) wsum[threadIdx.x >> 6] = s;
    __syncthreads();
    if (threadIdx.x == 0) {
        float t = wsum[0] + wsum[1] + wsum[2] + wsum[3];
        atomicAdd(out, t * (1.0f / (BB * NN)));
    }
}

extern "C" void kernel_launch(void* const* d_in, const int* in_sizes, int n_in,
                              void* d_out, int out_size, void* d_ws, size_t ws_size,
                              hipStream_t stream) {
    const float* pred   = (const float*)d_in[0];
    const float* target = (const float*)d_in[1];
    // d_in[2] (batch, int64) ignored: sorted equal-size segments by construction.
    float* out = (float*)d_out;
    unsigned int* pmin = (unsigned int*)d_ws;      // 512 KiB of ws

    // 0x7f7f7f7f as float = 3.39e38 -> "+inf" for the uint-ordered min
    hipMemsetAsync(pmin, 0x7f, (size_t)TOTX * sizeof(unsigned int), stream);
    hipMemsetAsync(out, 0, sizeof(float), stream);

    dim3 grid(XT, BB, 2 * S);
    chamfer_partial<<<grid, T, 0, stream>>>(pred, target, pmin);
    chamfer_reduce<<<128, 256, 0, stream>>>((const float*)pmin, out);
}

// Round 3
// 101.707 us; speedup vs baseline: 1.3959x; 1.0286x over previous
//
#include <hip/hip_runtime.h>

// Chamfer distance: B=16 clouds, N=4096 points, D=3, fp32.
// d2(i,j) = xsq_i + (yw_j - 2 x_i.y_j); xsq_i constant over min_j.
// Inner: 3 fma + 1/2 min3 per pair = 3.5 VALU/pair (algorithmic floor for 3D).
//
// R3: M=16 x/thread halves ds_read_b128 per fma (R2 was LDS-pipe-bound at
// ~86% util; now ~43%). S=16 y-splits keeps grid=512 (2 blocks/CU, 8 waves).
// Register double-buffer of the y-pair hides LDS latency within a wave.

#define BB 16
#define NN 4096
#define T  256
#define M  16                   // x points per thread -> 4096 = whole cloud
#define S  16                   // y splits
#define YC (NN / S)             // 256 y per block

__global__ __launch_bounds__(T) void chamfer_partial(
    const float* __restrict__ pred,
    const float* __restrict__ target,
    unsigned int* __restrict__ pmin)   // 2*BB*NN uints, pre-set to 0x7f7f7f7f
{
    __shared__ float4 ys[YC];          // 4 KiB

    const int b   = blockIdx.y;
    const int dir = blockIdx.z >> 4;
    const int yc  = blockIdx.z & 15;
    const float* xb = (dir ? target : pred) + (size_t)b * NN * 3;
    const float* yb = (dir ? pred : target) + (size_t)b * NN * 3 + (size_t)yc * YC * 3;

    {
        int j = threadIdx.x;           // YC == T: one y per thread
        float y0 = yb[3 * j + 0];
        float y1 = yb[3 * j + 1];
        float y2 = yb[3 * j + 2];
        ys[j] = make_float4(-2.f * y0, -2.f * y1, -2.f * y2,
                            fmaf(y0, y0, fmaf(y1, y1, y2 * y2)));
    }
    __syncthreads();

    float x0[M], x1[M], x2[M], xsq[M], mn[M];
#pragma unroll
    for (int m = 0; m < M; ++m) {
        int xi = threadIdx.x + m * T;
        float a = xb[3 * xi + 0];
        float c = xb[3 * xi + 1];
        float d = xb[3 * xi + 2];
        x0[m] = a; x1[m] = c; x2[m] = d;
        xsq[m] = fmaf(a, a, fmaf(c, c, d * d));
        mn[m]  = 3.402823466e38f;
    }

    float4 ya = ys[0], yv = ys[1];
    for (int j = 0; j < YC - 2; j += 2) {
        float4 na = ys[j + 2];         // prefetch next pair into registers
        float4 nv = ys[j + 3];
#pragma unroll
        for (int m = 0; m < M; ++m) {
            float fa = fmaf(x0[m], ya.x, fmaf(x1[m], ya.y, fmaf(x2[m], ya.z, ya.w)));
            float fb = fmaf(x0[m], yv.x, fmaf(x1[m], yv.y, fmaf(x2[m], yv.z, yv.w)));
            mn[m] = fminf(fminf(mn[m], fa), fb);   // -> v_min3_f32
        }
        ya = na; yv = nv;
    }
#pragma unroll
    for (int m = 0; m < M; ++m) {      // last pair
        float fa = fmaf(x0[m], ya.x, fmaf(x1[m], ya.y, fmaf(x2[m], ya.z, ya.w)));
        float fb = fmaf(x0[m], yv.x, fmaf(x1[m], yv.y, fmaf(x2[m], yv.z, yv.w)));
        mn[m] = fminf(fminf(mn[m], fa), fb);
    }

    const int obase = dir * (BB * NN) + b * NN + threadIdx.x;
#pragma unroll
    for (int m = 0; m < M; ++m) {
        float v = fmaxf(mn[m] + xsq[m], 0.f);      // true d2 >= 0; uint order ok
        atomicMin(&pmin[obase + m * T], __float_as_uint(v));
    }
}

#define TOTX (2 * BB * NN)   // 131072

__global__ __launch_bounds__(256) void chamfer_reduce(
    const float* __restrict__ pmin, float* __restrict__ out)
{
    float s = 0.f;
    for (int i = blockIdx.x * 256 + threadIdx.x; i < TOTX; i += gridDim.x * 256)
        s += pmin[i];
#pragma unroll
    for (int off = 32; off > 0; off >>= 1)
        s += __shfl_down(s, off, 64);
    __shared__ float wsum[4];
    if ((threadIdx.x & 63) == 0) wsum[threadIdx.x >> 6] = s;
    __syncthreads();
    if (threadIdx.x == 0) {
        float t = wsum[0] + wsum[1] + wsum[2] + wsum[3];
        atomicAdd(out, t * (1.0f / (BB * NN)));
    }
}

extern "C" void kernel_launch(void* const* d_in, const int* in_sizes, int n_in,
                              void* d_out, int out_size, void* d_ws, size_t ws_size,
                              hipStream_t stream) {
    const float* pred   = (const float*)d_in[0];
    const float* target = (const float*)d_in[1];
    // d_in[2] (batch, int64) ignored: sorted equal-size segments by construction.
    float* out = (float*)d_out;
    unsigned int* pmin = (unsigned int*)d_ws;      // 512 KiB of ws

    // 0x7f7f7f7f as float = 3.39e38 -> "+inf" for the uint-ordered min
    hipMemsetAsync(pmin, 0x7f, (size_t)TOTX * sizeof(unsigned int), stream);
    hipMemsetAsync(out, 0, sizeof(float), stream);

    dim3 grid(1, BB, 2 * S);
    chamfer_partial<<<grid, T, 0, stream>>>(pred, target, pmin);
    chamfer_reduce<<<128, 256, 0, stream>>>((const float*)pmin, out);
}